// Round 13
// baseline (222.186 us; speedup 1.0000x reference)
//
#include <hip/hip_runtime.h>
#include <stdint.h>

typedef uint16_t u16;
typedef uint32_t u32;
typedef __attribute__((ext_vector_type(4))) float f32x4;
typedef __attribute__((ext_vector_type(4))) unsigned short us4;

#define NB   16
#define NN   512
#define FF   625      // H*W
#define FH   937      // int(625*1.5)
#define ROWS 8192     // NB*NN
#define KS1  1280     // [X(625) pad->640 | t1(625) pad->640]
#define KS2  1920     // [h(937) pad->960 | t2(937) pad->960]
#define NPX  640      // padded F   (t1 cols / Xt rows per batch)
#define NPH  960      // padded Fh  (ht rows per batch)
#define F4   160      // 640/4 f32x4 slots per padded X row
#define GQ   4        // att-adjacent rows per build_L block

using frag_ab = __attribute__((ext_vector_type(8))) short;  // 8 bf16
using frag_cd = __attribute__((ext_vector_type(4))) float;  // 4 fp32

__device__ __forceinline__ u16 f32_bf16(float f) {
  union { float f; uint32_t u; } x; x.f = f;
  uint32_t r = x.u + 0x7fffu + ((x.u >> 16) & 1u);   // RNE
  return (u16)(r >> 16);
}
__device__ __forceinline__ void gload_lds16(const void* g, void* l) {
  __builtin_amdgcn_global_load_lds((__attribute__((address_space(1))) void*)g,
                                   (__attribute__((address_space(3))) void*)l,
                                   16, 0, 0);
}

// ---------------------------------------------------------------------------
// prep (R10-proven, R14 layout): single-pass fused, sort first, unioned LDS.
//  [0,16)        att rank-sort per batch -> order[b][512], att_s[b][512]
//  [16,1040)     fused: x4 -> Xpad + Xcat(lo) + Xt in ONE pass (x4 read once)
//  [1040,2320)   W1 -> W1t [1024][KS1]
//  [2320,3520)   W2 -> W2t [640][KS2]
// ---------------------------------------------------------------------------
__global__ __launch_bounds__(256) void prep(
    const float* __restrict__ x4, const float* __restrict__ att,
    const float* __restrict__ W1, const float* __restrict__ W2,
    f32x4* __restrict__ Xpad, u16* __restrict__ Xcat, u16* __restrict__ Xt,
    u16* __restrict__ W1t, u16* __restrict__ W2t,
    u16* __restrict__ order, float* __restrict__ att_s)
{
  __shared__ __align__(16) float smem[2112];   // 8448 B, unioned across branches
  const int blk = blockIdx.x;
  const int tid = threadIdx.x;

  if (blk < 16) {
    float* a_sh = smem;
    const int b = blk;
    a_sh[tid]       = att[b * NN + tid];
    a_sh[tid + 256] = att[b * NN + tid + 256];
    __syncthreads();
    #pragma unroll
    for (int h = 0; h < 2; ++h) {
      const int i = tid + h * 256;
      const float ai = a_sh[i];
      int r = 0;
      for (int j = 0; j < NN; ++j) {
        const float aj = a_sh[j];
        r += (aj < ai) || (aj == ai && j < i);
      }
      order[(size_t)b * NN + r] = (u16)i;
      att_s[(size_t)b * NN + r] = ai;
    }
  } else if (blk < 1040) {
    float* T = smem;
    const int idx = blk - 16;
    const int xcd = idx & 7, sub = idx >> 3;    // sub 0..127
    const int b = xcd * 2 + (sub >> 6);
    const int rr = sub & 63;
    const int q = rr >> 4;                      // f-quarter 0..3
    const int nt = rr & 15;                     // node-tile 0..15
    const int node0 = nt * 32;
    const int tx = tid & 31, ty = tid >> 5;
    const int lrow = tid >> 3, lcol = tid & 7;

    int buf = 0;
    {
      const int f0 = q * 160;
      #pragma unroll
      for (int r = 0; r < 4; ++r) {
        const int node = node0 + ty + r * 8;
        const int f = f0 + tx;
        T[(ty + r * 8) * 33 + tx] = (f < FF) ? x4[((size_t)b * NN + node) * FF + f] : 0.f;
      }
    }
    __syncthreads();

    for (int c = 0; c < 5; ++c) {
      const int f0 = q * 160 + c * 32;
      float vnext[4];
      const bool has = (c + 1 < 5);
      if (has) {
        const int fn = f0 + 32 + tx;
        #pragma unroll
        for (int r = 0; r < 4; ++r) {
          const int node = node0 + ty + r * 8;
          vnext[r] = (fn < FF) ? x4[((size_t)b * NN + node) * FF + fn] : 0.f;
        }
      }
      {
        const int node_l = lrow, k4s = lcol;
        const size_t grow = (size_t)b * NN + node0 + node_l;
        const int k4 = q * 40 + c * 8 + k4s;
        f32x4 v; us4 o;
        #pragma unroll
        for (int t = 0; t < 4; ++t) {
          const float x = T[buf * 1056 + node_l * 33 + k4s * 4 + t];
          v[t] = x; o[t] = f32_bf16(x);
        }
        Xpad[grow * F4 + k4] = v;
        *(us4*)(Xcat + grow * KS1 + k4 * 4) = o;
      }
      {
        const int fl = lrow, nl = lcol;
        const int f = f0 + fl;
        us4 ov;
        #pragma unroll
        for (int t = 0; t < 4; ++t)
          ov[t] = f32_bf16(T[buf * 1056 + (nl * 4 + t) * 33 + fl]);
        *(us4*)(Xt + ((size_t)b * NPX + f) * 512 + node0 + nl * 4) = ov;
      }
      if (has) {
        #pragma unroll
        for (int r = 0; r < 4; ++r)
          T[(buf ^ 1) * 1056 + (ty + r * 8) * 33 + tx] = vnext[r];
        __syncthreads();
        buf ^= 1;
      }
    }
  } else if (blk < 2320) {
    float (*tile)[33] = (float(*)[33])smem;
    const int bb = blk - 1040;                  // 40 kt x 32 nt
    const int kt = bb % 40, nt = bb / 40;
    const int tx = tid & 31, ty = tid >> 5;
    #pragma unroll
    for (int r = 0; r < 4; ++r) {
      int k = kt * 32 + ty + r * 8;
      int n = nt * 32 + tx;
      float v = 0.f;
      int c = -1, kk = 0;
      if (k < 625) { c = 0; kk = k; }
      else if (k >= 640 && k < 1265) { c = 1; kk = k - 640; }
      if (c >= 0 && n < FH) v = W1[((size_t)c * 625 + kk) * FH + n];
      tile[ty + r * 8][tx] = v;
    }
    __syncthreads();
    #pragma unroll
    for (int r = 0; r < 4; ++r) {
      int n = nt * 32 + ty + r * 8;
      int k = kt * 32 + tx;
      W1t[(size_t)n * KS1 + k] = f32_bf16(tile[tx][ty + r * 8]);
    }
  } else {
    float (*tile)[33] = (float(*)[33])smem;
    const int bb = blk - 2320;                  // 60 kt x 20 nt
    const int kt = bb % 60, nt = bb / 60;
    const int tx = tid & 31, ty = tid >> 5;
    #pragma unroll
    for (int r = 0; r < 4; ++r) {
      int k = kt * 32 + ty + r * 8;
      int n = nt * 32 + tx;
      float v = 0.f;
      int c = -1, kk = 0;
      if (k < 937) { c = 0; kk = k; }
      else if (k >= 960 && k < 1897) { c = 1; kk = k - 960; }
      if (c >= 0 && n < FF) v = W2[((size_t)c * 937 + kk) * FF + n];
      tile[ty + r * 8][tx] = v;
    }
    __syncthreads();
    #pragma unroll
    for (int r = 0; r < 4; ++r) {
      int n = nt * 32 + ty + r * 8;
      int k = kt * 32 + tx;
      W2t[(size_t)n * KS2 + k] = f32_bf16(tile[tx][ty + r * 8]);
    }
  }
}

// ---------------------------------------------------------------------------
// build_L (R9-proven): att-sorted row grouping, GQ=4 rows/block, contiguous
// sorted candidate window + exact per-row recheck. Xj loaded once per 4 rows.
// ---------------------------------------------------------------------------
__global__ __launch_bounds__(256) void build_L(
    const f32x4* __restrict__ Xpad,   // [ROWS][160]
    const u16* __restrict__ order,    // [NB][512]
    const float* __restrict__ att_s,  // [NB][512] ascending
    u16* __restrict__ L)              // [NB][512][512] bf16 row-major
{
  __shared__ float atts[512];
  __shared__ u16 ords[512];
  __shared__ u16 cand[512];
  __shared__ u16 flag[GQ][512];
  __shared__ int ncand, naccs[GQ];

  const int tid = threadIdx.x;
  const int blk = blockIdx.x;
  const int xcd = blk & 7, sub = blk >> 3;     // sub 0..255
  const int b = xcd * 2 + (sub >> 7);
  const int p0 = (sub & 127) * GQ;
  const f32x4* Xb4 = Xpad + (size_t)b * NN * F4;

  atts[tid]       = att_s[b * NN + tid];
  atts[tid + 256] = att_s[b * NN + tid + 256];
  ords[tid]       = order[b * NN + tid];
  ords[tid + 256] = order[b * NN + tid + 256];
  {
    u32* fz = (u32*)&flag[0][0];               // GQ*512 u16 = 1024 u32
    #pragma unroll
    for (int s = 0; s < GQ; ++s) fz[tid + s * 256] = 0;
  }
  if (tid == 0) ncand = 0;
  if (tid < GQ) naccs[tid] = 0;
  __syncthreads();

  float av[GQ]; int ig[GQ];
  #pragma unroll
  for (int g = 0; g < GQ; ++g) { av[g] = atts[p0 + g]; ig[g] = ords[p0 + g]; }
  if (tid < GQ) flag[tid][ords[p0 + tid]] = 1;   // self (A+I diagonal)

  {
    const float lo = av[0] - 0.0501f, hi = av[GQ - 1] + 0.0501f;
    const bool q0 = (atts[tid] >= lo) && (atts[tid] <= hi);
    const bool q1 = (atts[tid + 256] >= lo) && (atts[tid + 256] <= hi);
    const unsigned long long m0 = __ballot(q0);
    const unsigned long long m1 = __ballot(q1);
    const int c0 = __popcll(m0);
    const int c1 = __popcll(m1);
    const int lane = tid & 63;
    int base = 0;
    if (lane == 0 && (c0 + c1)) base = atomicAdd(&ncand, c0 + c1);
    base = __shfl(base, 0, 64);
    const unsigned long long below = (1ull << lane) - 1ull;
    if (q0) cand[base + __popcll(m0 & below)] = (u16)tid;
    if (q1) cand[base + c0 + __popcll(m1 & below)] = (u16)(tid + 256);
  }
  __syncthreads();
  const int nc = ncand;

  const int hl = tid & 31;
  const int hw = tid >> 5;

  f32x4 xi[GQ][5];
  #pragma unroll
  for (int g = 0; g < GQ; ++g) {
    const f32x4* Xi = Xb4 + (size_t)ig[g] * F4;
    #pragma unroll
    for (int s = 0; s < 5; ++s) xi[g][s] = Xi[s * 32 + hl];
  }

  for (int c = hw; c < nc; c += 8) {
    const int p = cand[c];
    const int j = ords[p];
    const float aj = atts[p];
    const f32x4* Xj = Xb4 + (size_t)j * F4;
    f32x4 xj[5];
    #pragma unroll
    for (int s = 0; s < 5; ++s) xj[s] = Xj[s * 32 + hl];

    float pd[GQ];
    #pragma unroll
    for (int g = 0; g < GQ; ++g) {
      float p2 = 0.f;   // EXACT summation order of the original per-row kernel
      #pragma unroll
      for (int t = 0; t < 4; ++t) {
        p2 += fabsf(xi[g][0][t] - xj[0][t]) + fabsf(xi[g][1][t] - xj[1][t])
            + fabsf(xi[g][2][t] - xj[2][t]) + fabsf(xi[g][3][t] - xj[3][t])
            + fabsf(xi[g][4][t] - xj[4][t]);
      }
      pd[g] = p2;
    }
    #pragma unroll
    for (int off = 16; off; off >>= 1) {
      #pragma unroll
      for (int g = 0; g < GQ; ++g) pd[g] += __shfl_xor(pd[g], off, 64);
    }
    if (hl == 0) {
      #pragma unroll
      for (int g = 0; g < GQ; ++g) {
        if (pd[g] <= 180.0f && fabsf(av[g] - aj) <= 0.05f && j != ig[g]) {
          flag[g][j] = 1;
          atomicAdd(&naccs[g], 1);
        }
      }
    }
  }
  __syncthreads();

  #pragma unroll
  for (int g = 0; g < GQ; ++g) {
    const u16 dv = f32_bf16(1.0f / (float)(naccs[g] + 1));
    const long row = (long)b * NN + ig[g];
    const u32 lo2 = flag[g][2 * tid]     ? (u32)dv : 0u;
    const u32 hi2 = flag[g][2 * tid + 1] ? (u32)dv : 0u;
    *(u32*)(L + (size_t)row * 512 + 2 * tid) = lo2 | (hi2 << 16);
  }
}

// ---------------------------------------------------------------------------
// gemm1_256 (R19): 256M x 128N tile, 512 threads / 8 waves (4M x 2N, each
// wave 64x64 out), BK=64, LDS double-buffered (96KB -> 1 block/CU, grid
// 32x8 = 256 blocks = exactly 1/CU). The lever vs the 2-barrier core:
// COUNTED s_waitcnt vmcnt(6) + raw s_barrier — next tile's 6 loads stay in
// flight across the barrier (never drains to 0 mid-loop; R15's failure was
// __syncthreads' implicit vmcnt(0) drain). setprio(1) around MFMA (T5 pays
// with 8-wave role split). Same XOR swizzle + K-order as proven core ->
// bit-identical accumulation. Epilogue = gemm1's bias+relu+bf16 + WT(ht).
// ---------------------------------------------------------------------------
__global__ __launch_bounds__(512) void gemm1_256(
    const u16* __restrict__ A,       // Xcat [8192][1280]
    const u16* __restrict__ Bt,      // W1t  [1024][1280]
    const float* __restrict__ bias, u16* __restrict__ C,   // hcat, ldc=KS2
    u16* __restrict__ Ct)            // ht [NB][960][512]
{
  __shared__ __align__(16) u16 Ash[2][256 * 64];   // 64 KB
  __shared__ __align__(16) u16 Bsh[2][128 * 64];   // 32 KB

  const int tid  = threadIdx.x;
  const int lane = tid & 63;
  const int wave = tid >> 6;          // 0..7
  const int wm = wave & 3;            // M-slot (64 rows)
  const int wn = wave >> 2;           // N-slot (64 cols)
  const int q = lane >> 4, l16 = lane & 15;

  const int x = blockIdx.x;           // 0..31 M-tiles
  const int mt = ((x & 7) << 2) | (x >> 3);   // XCD-aligned (8 xcd x 4)
  const int nt = blockIdx.y;          // 0..7 N-tiles
  const u16* At  = A  + (size_t)mt * 256 * KS1;
  const u16* Btt = Bt + (size_t)nt * 128 * KS1;

  // staging: r=0..3 A rows 0..255, r=0..1 B rows 0..127; 6 loads/lane/K-step
  const u16* pa[4]; const u16* pb[2];
  #pragma unroll
  for (int r = 0; r < 4; ++r) {
    const int ci = r * 512 + tid;
    const int row = ci >> 3, cpos = ci & 7;
    pa[r] = At + (size_t)row * KS1 + (cpos ^ (row & 7)) * 8;
  }
  #pragma unroll
  for (int r = 0; r < 2; ++r) {
    const int ci = r * 512 + tid;
    const int row = ci >> 3, cpos = ci & 7;
    pb[r] = Btt + (size_t)row * KS1 + (cpos ^ (row & 7)) * 8;
  }
  const int wbase = (tid & 448) * 8;  // wave*512 u16 (64 lanes x 16B)

  int aoff[4][2], boff[4][2];
  #pragma unroll
  for (int mi = 0; mi < 4; ++mi) {
    const int row = wm * 64 + mi * 16 + l16;
    aoff[mi][0] = row * 64 + ((q    ) ^ (l16 & 7)) * 8;
    aoff[mi][1] = row * 64 + ((q + 4) ^ (l16 & 7)) * 8;
  }
  #pragma unroll
  for (int ni = 0; ni < 4; ++ni) {
    const int row = wn * 64 + ni * 16 + l16;
    boff[ni][0] = row * 64 + ((q    ) ^ (l16 & 7)) * 8;
    boff[ni][1] = row * 64 + ((q + 4) ^ (l16 & 7)) * 8;
  }

  frag_cd acc[4][4] = {};
  constexpr int KT = KS1 / 64;        // 20

  // prologue: stage tile 0 into buf 0
  #pragma unroll
  for (int r = 0; r < 4; ++r) { gload_lds16(pa[r], &Ash[0][r * 4096 + wbase]); pa[r] += 64; }
  #pragma unroll
  for (int r = 0; r < 2; ++r) { gload_lds16(pb[r], &Bsh[0][r * 4096 + wbase]); pb[r] += 64; }

  int cur = 0;
  for (int kt = 0; kt < KT; ++kt) {
    if (kt + 1 < KT) {
      const int nxt = cur ^ 1;
      #pragma unroll
      for (int r = 0; r < 4; ++r) { gload_lds16(pa[r], &Ash[nxt][r * 4096 + wbase]); pa[r] += 64; }
      #pragma unroll
      for (int r = 0; r < 2; ++r) { gload_lds16(pb[r], &Bsh[nxt][r * 4096 + wbase]); pb[r] += 64; }
      asm volatile("s_waitcnt vmcnt(6)" ::: "memory");  // tile kt landed; 6 in flight
    } else {
      asm volatile("s_waitcnt vmcnt(0)" ::: "memory");  // final tile landed
    }
    __builtin_amdgcn_s_barrier();
    __builtin_amdgcn_sched_barrier(0);   // pin ds_read/MFMA below the barrier

    const u16* A0 = &Ash[cur][0];
    const u16* B0 = &Bsh[cur][0];
    __builtin_amdgcn_s_setprio(1);
    #pragma unroll
    for (int kk = 0; kk < 2; ++kk) {
      frag_ab av[4], bv[4];
      #pragma unroll
      for (int mi = 0; mi < 4; ++mi) av[mi] = *(const frag_ab*)&A0[aoff[mi][kk]];
      #pragma unroll
      for (int ni = 0; ni < 4; ++ni) bv[ni] = *(const frag_ab*)&B0[boff[ni][kk]];
      #pragma unroll
      for (int mi = 0; mi < 4; ++mi)
        #pragma unroll
        for (int ni = 0; ni < 4; ++ni)
          acc[mi][ni] = __builtin_amdgcn_mfma_f32_16x16x32_bf16(
              av[mi], bv[ni], acc[mi][ni], 0, 0, 0);
    }
    __builtin_amdgcn_s_setprio(0);
    __builtin_amdgcn_sched_barrier(0);   // keep compute above the reuse barrier
    __builtin_amdgcn_s_barrier();        // all reads of buf[cur] done before overwrite
    cur ^= 1;
  }

  // epilogue: bias + relu + bf16 store into hcat, plus transposed ht store
  const int col0 = nt * 128;
  const long crow0 = (long)mt * 256;
  const long bb = crow0 >> 9;                      // batch (tile within one batch)
  #pragma unroll
  for (int ni = 0; ni < 4; ++ni) {
    const int col = col0 + wn * 64 + ni * 16 + l16;
    if (col >= NPH) continue;                      // store cols < 960
    const bool ok = (col < FH);
    const float bvv = ok ? bias[col] : 0.f;
    #pragma unroll
    for (int mi = 0; mi < 4; ++mi) {
      us4 tv;
      #pragma unroll
      for (int r = 0; r < 4; ++r) {
        const long rowg = crow0 + wm * 64 + mi * 16 + q * 4 + r;
        float v = acc[mi][ni][r];
        v += bvv;
        v = fmaxf(v, 0.f);
        if (!ok) v = 0.f;
        const u16 v16 = f32_bf16(v);
        C[rowg * (size_t)KS2 + col] = v16;
        tv[r] = v16;
      }
      const int node = (int)(crow0 & 511) + wm * 64 + mi * 16 + q * 4;
      *(us4*)(Ct + ((size_t)bb * NPH + col) * 512 + node) = tv;
    }
  }
}

// ---------------------------------------------------------------------------
// gemm_core (R14-proven single-buffer schedule). 128M x NTILE-N tile, BK=64,
// XOR chunk swizzle. Epilogue: store cols < NSTORE; value = col<NREAL ?
// f(acc) : 0. WT: also store bf16 transposed per batch into Ct.
// ---------------------------------------------------------------------------
template <int KS, int NTILE, int NREAL, int NSTORE, bool RELU, bool BIAS,
          bool OUT_BF16, bool WT>
__device__ __forceinline__ void gemm_core(
    const u16* __restrict__ At,      // A tile base: rows 0..127, stride KS
    const u16* __restrict__ Btt,     // B^T tile base: rows 0..NTILE-1, stride KS
    const float* __restrict__ bias, void* __restrict__ C,
    u16* __restrict__ Ct,            // transposed out (WT only)
    long crow0, int col0, int ldc)
{
  constexpr int NI = NTILE / 32;
  constexpr int BR = NTILE / 32;
  __shared__ __align__(16) u16 Ash[128 * 64];
  __shared__ __align__(16) u16 Bsh[NTILE * 64];

  const int tid  = threadIdx.x;
  const int lane = tid & 63;
  const int wave = tid >> 6;
  const int wm = wave & 1, wn = wave >> 1;
  const int q = lane >> 4, l16 = lane & 15;

  const u16* pa[4]; const u16* pb[BR];
  #pragma unroll
  for (int r = 0; r < 4; ++r) {
    const int ci = r * 256 + tid;
    const int row = ci >> 3, cpos = ci & 7;
    pa[r] = At + (size_t)row * KS + (cpos ^ (row & 7)) * 8;
  }
  #pragma unroll
  for (int r = 0; r < BR; ++r) {
    const int ci = r * 256 + tid;
    const int row = ci >> 3, cpos = ci & 7;
    pb[r] = Btt + (size_t)row * KS + (cpos ^ (row & 7)) * 8;
  }
  const int wbase = (tid & 192) * 8;

  const frag_ab* fA[4][2]; const frag_ab* fB[NI][2];
  #pragma unroll
  for (int mi = 0; mi < 4; ++mi) {
    const int row = wm * 64 + mi * 16 + l16;
    fA[mi][0] = (const frag_ab*)&Ash[row * 64 + ((q    ) ^ (l16 & 7)) * 8];
    fA[mi][1] = (const frag_ab*)&Ash[row * 64 + ((q + 4) ^ (l16 & 7)) * 8];
  }
  #pragma unroll
  for (int ni = 0; ni < NI; ++ni) {
    const int row = wn * (NTILE / 2) + ni * 16 + l16;
    fB[ni][0] = (const frag_ab*)&Bsh[row * 64 + ((q    ) ^ (l16 & 7)) * 8];
    fB[ni][1] = (const frag_ab*)&Bsh[row * 64 + ((q + 4) ^ (l16 & 7)) * 8];
  }

  frag_cd acc[4][NI] = {};

  constexpr int KT = KS / 64;
  for (int kt = 0; kt < KT; ++kt) {
    __syncthreads();
    #pragma unroll
    for (int r = 0; r < 4; ++r) { gload_lds16(pa[r], &Ash[r * 2048 + wbase]); pa[r] += 64; }
    #pragma unroll
    for (int r = 0; r < BR; ++r) { gload_lds16(pb[r], &Bsh[r * 2048 + wbase]); pb[r] += 64; }
    __syncthreads();

    #pragma unroll
    for (int kk = 0; kk < 2; ++kk) {
      frag_ab av[4], bv[NI];
      #pragma unroll
      for (int mi = 0; mi < 4; ++mi) av[mi] = *fA[mi][kk];
      #pragma unroll
      for (int ni = 0; ni < NI; ++ni) bv[ni] = *fB[ni][kk];
      #pragma unroll
      for (int mi = 0; mi < 4; ++mi)
        #pragma unroll
        for (int ni = 0; ni < NI; ++ni)
          acc[mi][ni] = __builtin_amdgcn_mfma_f32_16x16x32_bf16(
              av[mi], bv[ni], acc[mi][ni], 0, 0, 0);
    }
  }

  #pragma unroll
  for (int ni = 0; ni < NI; ++ni) {
    const int col = col0 + wn * (NTILE / 2) + ni * 16 + l16;
    if (col >= NSTORE) continue;
    const bool ok = (col < NREAL);
    float bvv = 0.f;
    if (BIAS) bvv = ok ? bias[col] : 0.f;
    #pragma unroll
    for (int mi = 0; mi < 4; ++mi) {
      us4 tv;
      #pragma unroll
      for (int r = 0; r < 4; ++r) {
        const long rowg = crow0 + wm * 64 + mi * 16 + q * 4 + r;
        float v = acc[mi][ni][r];
        if (BIAS) v += bvv;
        if (RELU) v = fmaxf(v, 0.f);
        if (!ok) v = 0.f;
        if (OUT_BF16) {
          const u16 v16 = f32_bf16(v);
          ((u16*)C)[rowg * (size_t)ldc + col] = v16;
          if (WT) tv[r] = v16;
        } else {
          ((float*)C)[rowg * (size_t)ldc + col] = v;
        }
      }
      if (WT) {
        const long bb = crow0 >> 9;
        const int node = (int)(crow0 & 511) + wm * 64 + mi * 16 + q * 4;
        *(us4*)(Ct + ((size_t)bb * NPH + col) * 512 + node) = tv;
      }
    }
  }
}

// dense: grid (64, Nt); XCD-aligned m-tile (R6)
template <int KS, int NTILE, int NREAL, int NSTORE, bool RELU, bool BIAS,
          bool OUT_BF16, bool WT>
__global__ __launch_bounds__(256) void gemm_dense(
    const u16* __restrict__ A, const u16* __restrict__ Bt,
    const float* __restrict__ bias, void* __restrict__ C,
    u16* __restrict__ Ct, int ldc)
{
  const int x = blockIdx.x;
  const int mt = ((x & 7) << 3) | (x >> 3);
  gemm_core<KS, NTILE, NREAL, NSTORE, RELU, BIAS, OUT_BF16, WT>(
      A + (size_t)mt * 128 * KS, Bt + (size_t)blockIdx.y * NTILE * KS,
      bias, C, Ct, (long)mt * 128, blockIdx.y * NTILE, ldc);
}

// batched spmm: t = L_b · B_b^T; batch b on XCD b/2 (L2-local L/Bt/C).
template <int NP>
__global__ __launch_bounds__(256) void spmm(
    const u16* __restrict__ L, const u16* __restrict__ Bt,
    u16* __restrict__ C, int ldc)
{
  constexpr int TPB = 4 * (NP / 64);
  const int blk = blockIdx.x;
  const int xcd = blk & 7, sub = blk >> 3;
  const int b = xcd * 2 + sub / TPB;
  const int t = sub % TPB;
  const int mt = t & 3, nt = t >> 2;
  gemm_core<512, 64, NP, NP, false, false, true, false>(
      L + ((size_t)b * 512 + mt * 128) * 512,
      Bt + ((size_t)b * NP + nt * 64) * 512,
      nullptr, C, nullptr, (long)b * 512 + mt * 128, nt * 64, ldc);
}

// ---------------------------------------------------------------------------
extern "C" void kernel_launch(void* const* d_in, const int* in_sizes, int n_in,
                              void* d_out, int out_size, void* d_ws, size_t ws_size,
                              hipStream_t stream) {
  const float* x4  = (const float*)d_in[0];
  const float* att = (const float*)d_in[1];
  const float* W1  = (const float*)d_in[2];
  const float* b1  = (const float*)d_in[3];
  const float* W2  = (const float*)d_in[4];
  const float* b2  = (const float*)d_in[5];
  float* out = (float*)d_out;

  char* ws = (char*)d_ws;
  f32x4* Xpad = (f32x4*)ws;                                 // 20.97 MB
  u16* ht = (u16*)ws;       ws += (size_t)ROWS * F4 * 16;   // ht (15.7 MB) aliases
                                                            // Xpad: dead after build_L
  u16* Xcat = (u16*)ws;  ws += (size_t)ROWS * KS1 * 2;      // 20.97 MB
  u16* hcat = (u16*)ws;  ws += (size_t)ROWS * KS2 * 2;      // 31.46 MB
  u16* W1t  = (u16*)ws;  ws += (size_t)1024 * KS1 * 2;      //  2.62 MB
  u16* W2t  = (u16*)ws;  ws += (size_t)640 * KS2 * 2;       //  2.46 MB
  u16* Lm   = (u16*)ws;  ws += (size_t)NB * 512 * 512 * 2;  //  8.39 MB
  u16* Xt   = (u16*)ws;  ws += (size_t)NB * NPX * 512 * 2;  // 10.49 MB
  float* att_s = (float*)ws; ws += (size_t)NB * NN * 4;     // 32 KB
  u16* order_  = (u16*)ws;   ws += (size_t)NB * NN * 2;     // 16 KB

  prep<<<dim3(3520), 256, 0, stream>>>(x4, att, W1, W2, Xpad, Xcat, Xt,
                                       W1t, W2t, order_, att_s);
  build_L<<<dim3(2048), 256, 0, stream>>>(Xpad, order_, att_s, Lm);
  spmm<NPX><<<dim3(640), 256, 0, stream>>>(Lm, Xt, Xcat + NPX, KS1);
  // gemm1 (R19): 256x128-tile, 8-wave, counted-vmcnt pipelined; emits hcat + ht.
  gemm1_256<<<dim3(32, 8), 512, 0, stream>>>(Xcat, W1t, b1, hcat, ht);
  spmm<NPH><<<dim3(960), 256, 0, stream>>>(Lm, ht, hcat + NPH, KS2);
  gemm_dense<KS2, 64, FF, FF, true, true, false, false><<<dim3(64, 10), 256, 0, stream>>>(
      hcat, W2t, b2, (void*)out, nullptr, FF);
}

// Round 14
// 222.027 us; speedup vs baseline: 1.0007x; 1.0007x over previous
//
#include <hip/hip_runtime.h>
#include <stdint.h>

typedef uint16_t u16;
typedef uint32_t u32;
typedef __attribute__((ext_vector_type(4))) float f32x4;
typedef __attribute__((ext_vector_type(4))) unsigned short us4;

#define NB   16
#define NN   512
#define FF   625      // H*W
#define FH   937      // int(625*1.5)
#define ROWS 8192     // NB*NN
#define KS1  1280     // [X(625) pad->640 | t1(625) pad->640]
#define KS2  1920     // [h(937) pad->960 | t2(937) pad->960]
#define NPX  640      // padded F   (t1 cols / Xt rows per batch)
#define NPH  960      // padded Fh  (ht rows per batch)
#define F4   160      // 640/4 f32x4 slots per padded X row
#define GQ   4        // att-adjacent rows per build_L block

using frag_ab = __attribute__((ext_vector_type(8))) short;  // 8 bf16
using frag_cd = __attribute__((ext_vector_type(4))) float;  // 4 fp32

__device__ __forceinline__ u16 f32_bf16(float f) {
  union { float f; uint32_t u; } x; x.f = f;
  uint32_t r = x.u + 0x7fffu + ((x.u >> 16) & 1u);   // RNE
  return (u16)(r >> 16);
}
__device__ __forceinline__ void gload_lds16(const void* g, void* l) {
  __builtin_amdgcn_global_load_lds((__attribute__((address_space(1))) void*)g,
                                   (__attribute__((address_space(3))) void*)l,
                                   16, 0, 0);
}

// ---------------------------------------------------------------------------
// prep (R10-proven, R14 layout): single-pass fused, sort first, unioned LDS.
//  [0,16)        att rank-sort per batch -> order[b][512], att_s[b][512]
//  [16,1040)     fused: x4 -> Xpad + Xcat(lo) + Xt in ONE pass (x4 read once)
//  [1040,2320)   W1 -> W1t [1024][KS1]
//  [2320,3520)   W2 -> W2t [640][KS2]
// ---------------------------------------------------------------------------
__global__ __launch_bounds__(256) void prep(
    const float* __restrict__ x4, const float* __restrict__ att,
    const float* __restrict__ W1, const float* __restrict__ W2,
    f32x4* __restrict__ Xpad, u16* __restrict__ Xcat, u16* __restrict__ Xt,
    u16* __restrict__ W1t, u16* __restrict__ W2t,
    u16* __restrict__ order, float* __restrict__ att_s)
{
  __shared__ __align__(16) float smem[2112];   // 8448 B, unioned across branches
  const int blk = blockIdx.x;
  const int tid = threadIdx.x;

  if (blk < 16) {
    float* a_sh = smem;
    const int b = blk;
    a_sh[tid]       = att[b * NN + tid];
    a_sh[tid + 256] = att[b * NN + tid + 256];
    __syncthreads();
    #pragma unroll
    for (int h = 0; h < 2; ++h) {
      const int i = tid + h * 256;
      const float ai = a_sh[i];
      int r = 0;
      for (int j = 0; j < NN; ++j) {
        const float aj = a_sh[j];
        r += (aj < ai) || (aj == ai && j < i);
      }
      order[(size_t)b * NN + r] = (u16)i;
      att_s[(size_t)b * NN + r] = ai;
    }
  } else if (blk < 1040) {
    float* T = smem;
    const int idx = blk - 16;
    const int xcd = idx & 7, sub = idx >> 3;    // sub 0..127
    const int b = xcd * 2 + (sub >> 6);
    const int rr = sub & 63;
    const int q = rr >> 4;                      // f-quarter 0..3
    const int nt = rr & 15;                     // node-tile 0..15
    const int node0 = nt * 32;
    const int tx = tid & 31, ty = tid >> 5;
    const int lrow = tid >> 3, lcol = tid & 7;

    int buf = 0;
    {
      const int f0 = q * 160;
      #pragma unroll
      for (int r = 0; r < 4; ++r) {
        const int node = node0 + ty + r * 8;
        const int f = f0 + tx;
        T[(ty + r * 8) * 33 + tx] = (f < FF) ? x4[((size_t)b * NN + node) * FF + f] : 0.f;
      }
    }
    __syncthreads();

    for (int c = 0; c < 5; ++c) {
      const int f0 = q * 160 + c * 32;
      float vnext[4];
      const bool has = (c + 1 < 5);
      if (has) {
        const int fn = f0 + 32 + tx;
        #pragma unroll
        for (int r = 0; r < 4; ++r) {
          const int node = node0 + ty + r * 8;
          vnext[r] = (fn < FF) ? x4[((size_t)b * NN + node) * FF + fn] : 0.f;
        }
      }
      {
        const int node_l = lrow, k4s = lcol;
        const size_t grow = (size_t)b * NN + node0 + node_l;
        const int k4 = q * 40 + c * 8 + k4s;
        f32x4 v; us4 o;
        #pragma unroll
        for (int t = 0; t < 4; ++t) {
          const float x = T[buf * 1056 + node_l * 33 + k4s * 4 + t];
          v[t] = x; o[t] = f32_bf16(x);
        }
        Xpad[grow * F4 + k4] = v;
        *(us4*)(Xcat + grow * KS1 + k4 * 4) = o;
      }
      {
        const int fl = lrow, nl = lcol;
        const int f = f0 + fl;
        us4 ov;
        #pragma unroll
        for (int t = 0; t < 4; ++t)
          ov[t] = f32_bf16(T[buf * 1056 + (nl * 4 + t) * 33 + fl]);
        *(us4*)(Xt + ((size_t)b * NPX + f) * 512 + node0 + nl * 4) = ov;
      }
      if (has) {
        #pragma unroll
        for (int r = 0; r < 4; ++r)
          T[(buf ^ 1) * 1056 + (ty + r * 8) * 33 + tx] = vnext[r];
        __syncthreads();
        buf ^= 1;
      }
    }
  } else if (blk < 2320) {
    float (*tile)[33] = (float(*)[33])smem;
    const int bb = blk - 1040;                  // 40 kt x 32 nt
    const int kt = bb % 40, nt = bb / 40;
    const int tx = tid & 31, ty = tid >> 5;
    #pragma unroll
    for (int r = 0; r < 4; ++r) {
      int k = kt * 32 + ty + r * 8;
      int n = nt * 32 + tx;
      float v = 0.f;
      int c = -1, kk = 0;
      if (k < 625) { c = 0; kk = k; }
      else if (k >= 640 && k < 1265) { c = 1; kk = k - 640; }
      if (c >= 0 && n < FH) v = W1[((size_t)c * 625 + kk) * FH + n];
      tile[ty + r * 8][tx] = v;
    }
    __syncthreads();
    #pragma unroll
    for (int r = 0; r < 4; ++r) {
      int n = nt * 32 + ty + r * 8;
      int k = kt * 32 + tx;
      W1t[(size_t)n * KS1 + k] = f32_bf16(tile[tx][ty + r * 8]);
    }
  } else {
    float (*tile)[33] = (float(*)[33])smem;
    const int bb = blk - 2320;                  // 60 kt x 20 nt
    const int kt = bb % 60, nt = bb / 60;
    const int tx = tid & 31, ty = tid >> 5;
    #pragma unroll
    for (int r = 0; r < 4; ++r) {
      int k = kt * 32 + ty + r * 8;
      int n = nt * 32 + tx;
      float v = 0.f;
      int c = -1, kk = 0;
      if (k < 937) { c = 0; kk = k; }
      else if (k >= 960 && k < 1897) { c = 1; kk = k - 960; }
      if (c >= 0 && n < FF) v = W2[((size_t)c * 937 + kk) * FF + n];
      tile[ty + r * 8][tx] = v;
    }
    __syncthreads();
    #pragma unroll
    for (int r = 0; r < 4; ++r) {
      int n = nt * 32 + ty + r * 8;
      int k = kt * 32 + tx;
      W2t[(size_t)n * KS2 + k] = f32_bf16(tile[tx][ty + r * 8]);
    }
  }
}

// ---------------------------------------------------------------------------
// build_L (R9-proven): att-sorted row grouping, GQ=4 rows/block, contiguous
// sorted candidate window + exact per-row recheck. Xj loaded once per 4 rows.
// ---------------------------------------------------------------------------
__global__ __launch_bounds__(256) void build_L(
    const f32x4* __restrict__ Xpad,   // [ROWS][160]
    const u16* __restrict__ order,    // [NB][512]
    const float* __restrict__ att_s,  // [NB][512] ascending
    u16* __restrict__ L)              // [NB][512][512] bf16 row-major
{
  __shared__ float atts[512];
  __shared__ u16 ords[512];
  __shared__ u16 cand[512];
  __shared__ u16 flag[GQ][512];
  __shared__ int ncand, naccs[GQ];

  const int tid = threadIdx.x;
  const int blk = blockIdx.x;
  const int xcd = blk & 7, sub = blk >> 3;     // sub 0..255
  const int b = xcd * 2 + (sub >> 7);
  const int p0 = (sub & 127) * GQ;
  const f32x4* Xb4 = Xpad + (size_t)b * NN * F4;

  atts[tid]       = att_s[b * NN + tid];
  atts[tid + 256] = att_s[b * NN + tid + 256];
  ords[tid]       = order[b * NN + tid];
  ords[tid + 256] = order[b * NN + tid + 256];
  {
    u32* fz = (u32*)&flag[0][0];               // GQ*512 u16 = 1024 u32
    #pragma unroll
    for (int s = 0; s < GQ; ++s) fz[tid + s * 256] = 0;
  }
  if (tid == 0) ncand = 0;
  if (tid < GQ) naccs[tid] = 0;
  __syncthreads();

  float av[GQ]; int ig[GQ];
  #pragma unroll
  for (int g = 0; g < GQ; ++g) { av[g] = atts[p0 + g]; ig[g] = ords[p0 + g]; }
  if (tid < GQ) flag[tid][ords[p0 + tid]] = 1;   // self (A+I diagonal)

  {
    const float lo = av[0] - 0.0501f, hi = av[GQ - 1] + 0.0501f;
    const bool q0 = (atts[tid] >= lo) && (atts[tid] <= hi);
    const bool q1 = (atts[tid + 256] >= lo) && (atts[tid + 256] <= hi);
    const unsigned long long m0 = __ballot(q0);
    const unsigned long long m1 = __ballot(q1);
    const int c0 = __popcll(m0);
    const int c1 = __popcll(m1);
    const int lane = tid & 63;
    int base = 0;
    if (lane == 0 && (c0 + c1)) base = atomicAdd(&ncand, c0 + c1);
    base = __shfl(base, 0, 64);
    const unsigned long long below = (1ull << lane) - 1ull;
    if (q0) cand[base + __popcll(m0 & below)] = (u16)tid;
    if (q1) cand[base + c0 + __popcll(m1 & below)] = (u16)(tid + 256);
  }
  __syncthreads();
  const int nc = ncand;

  const int hl = tid & 31;
  const int hw = tid >> 5;

  f32x4 xi[GQ][5];
  #pragma unroll
  for (int g = 0; g < GQ; ++g) {
    const f32x4* Xi = Xb4 + (size_t)ig[g] * F4;
    #pragma unroll
    for (int s = 0; s < 5; ++s) xi[g][s] = Xi[s * 32 + hl];
  }

  for (int c = hw; c < nc; c += 8) {
    const int p = cand[c];
    const int j = ords[p];
    const float aj = atts[p];
    const f32x4* Xj = Xb4 + (size_t)j * F4;
    f32x4 xj[5];
    #pragma unroll
    for (int s = 0; s < 5; ++s) xj[s] = Xj[s * 32 + hl];

    float pd[GQ];
    #pragma unroll
    for (int g = 0; g < GQ; ++g) {
      float p2 = 0.f;   // EXACT summation order of the original per-row kernel
      #pragma unroll
      for (int t = 0; t < 4; ++t) {
        p2 += fabsf(xi[g][0][t] - xj[0][t]) + fabsf(xi[g][1][t] - xj[1][t])
            + fabsf(xi[g][2][t] - xj[2][t]) + fabsf(xi[g][3][t] - xj[3][t])
            + fabsf(xi[g][4][t] - xj[4][t]);
      }
      pd[g] = p2;
    }
    #pragma unroll
    for (int off = 16; off; off >>= 1) {
      #pragma unroll
      for (int g = 0; g < GQ; ++g) pd[g] += __shfl_xor(pd[g], off, 64);
    }
    if (hl == 0) {
      #pragma unroll
      for (int g = 0; g < GQ; ++g) {
        if (pd[g] <= 180.0f && fabsf(av[g] - aj) <= 0.05f && j != ig[g]) {
          flag[g][j] = 1;
          atomicAdd(&naccs[g], 1);
        }
      }
    }
  }
  __syncthreads();

  #pragma unroll
  for (int g = 0; g < GQ; ++g) {
    const u16 dv = f32_bf16(1.0f / (float)(naccs[g] + 1));
    const long row = (long)b * NN + ig[g];
    const u32 lo2 = flag[g][2 * tid]     ? (u32)dv : 0u;
    const u32 hi2 = flag[g][2 * tid + 1] ? (u32)dv : 0u;
    *(u32*)(L + (size_t)row * 512 + 2 * tid) = lo2 | (hi2 << 16);
  }
}

// ---------------------------------------------------------------------------
// gemm_core (R20): R14 schedule, generalized M-tile MT in {64,128}.
// MT=64 halves the tile rows -> grid doubles -> 2x blocks/CU (the TLP that
// hides the per-block staging drain; R15/R19 showed in-block pipelining
// can't). Only B is restaged more (B is small & L2-resident); A traffic is
// set by n-tile count and unchanged — unlike R16's N-split which doubled A.
// Wave layout: WM=MT/64 wave-rows x WN=4/WM wave-cols; staging/XOR-swizzle
// identity LDS[ci*8] = global[row*KS+(cpos^(row&7))*8] is MT-independent.
// Epilogue: store cols < NSTORE; value = col<NREAL ? f(acc) : 0.
// WT (R11-proven): also store bf16 transposed per batch into Ct.
// ---------------------------------------------------------------------------
template <int KS, int MT, int NTILE, int NREAL, int NSTORE, bool RELU, bool BIAS,
          bool OUT_BF16, bool WT>
__device__ __forceinline__ void gemm_core(
    const u16* __restrict__ At,      // A tile base: rows 0..MT-1, stride KS
    const u16* __restrict__ Btt,     // B^T tile base: rows 0..NTILE-1, stride KS
    const float* __restrict__ bias, void* __restrict__ C,
    u16* __restrict__ Ct,            // transposed out (WT only)
    long crow0, int col0, int ldc)
{
  constexpr int WM = MT / 64;        // wave rows (1 or 2)
  constexpr int WN = 4 / WM;         // wave cols (4 or 2)
  constexpr int NW = NTILE / WN;     // per-wave N width
  constexpr int NI = NW / 16;
  constexpr int AR = MT / 32;        // A staging rounds
  constexpr int BR = NTILE / 32;     // B staging rounds
  __shared__ __align__(16) u16 Ash[MT * 64];
  __shared__ __align__(16) u16 Bsh[NTILE * 64];

  const int tid  = threadIdx.x;
  const int lane = tid & 63;
  const int wave = tid >> 6;
  const int wm = (WM == 1) ? 0 : (wave & 1);
  const int wn = (WM == 1) ? wave : (wave >> 1);
  const int q = lane >> 4, l16 = lane & 15;

  const u16* pa[AR]; const u16* pb[BR];
  #pragma unroll
  for (int r = 0; r < AR; ++r) {
    const int ci = r * 256 + tid;
    const int row = ci >> 3, cpos = ci & 7;
    pa[r] = At + (size_t)row * KS + (cpos ^ (row & 7)) * 8;
  }
  #pragma unroll
  for (int r = 0; r < BR; ++r) {
    const int ci = r * 256 + tid;
    const int row = ci >> 3, cpos = ci & 7;
    pb[r] = Btt + (size_t)row * KS + (cpos ^ (row & 7)) * 8;
  }
  const int wbase = (tid & 192) * 8;

  const frag_ab* fA[4][2]; const frag_ab* fB[NI][2];
  #pragma unroll
  for (int mi = 0; mi < 4; ++mi) {
    const int row = wm * 64 + mi * 16 + l16;
    fA[mi][0] = (const frag_ab*)&Ash[row * 64 + ((q    ) ^ (l16 & 7)) * 8];
    fA[mi][1] = (const frag_ab*)&Ash[row * 64 + ((q + 4) ^ (l16 & 7)) * 8];
  }
  #pragma unroll
  for (int ni = 0; ni < NI; ++ni) {
    const int row = wn * NW + ni * 16 + l16;
    fB[ni][0] = (const frag_ab*)&Bsh[row * 64 + ((q    ) ^ (l16 & 7)) * 8];
    fB[ni][1] = (const frag_ab*)&Bsh[row * 64 + ((q + 4) ^ (l16 & 7)) * 8];
  }

  frag_cd acc[4][NI] = {};

  constexpr int KT = KS / 64;
  for (int kt = 0; kt < KT; ++kt) {
    __syncthreads();
    #pragma unroll
    for (int r = 0; r < AR; ++r) { gload_lds16(pa[r], &Ash[r * 2048 + wbase]); pa[r] += 64; }
    #pragma unroll
    for (int r = 0; r < BR; ++r) { gload_lds16(pb[r], &Bsh[r * 2048 + wbase]); pb[r] += 64; }
    __syncthreads();

    #pragma unroll
    for (int kk = 0; kk < 2; ++kk) {
      frag_ab av[4], bv[NI];
      #pragma unroll
      for (int mi = 0; mi < 4; ++mi) av[mi] = *fA[mi][kk];
      #pragma unroll
      for (int ni = 0; ni < NI; ++ni) bv[ni] = *fB[ni][kk];
      #pragma unroll
      for (int mi = 0; mi < 4; ++mi)
        #pragma unroll
        for (int ni = 0; ni < NI; ++ni)
          acc[mi][ni] = __builtin_amdgcn_mfma_f32_16x16x32_bf16(
              av[mi], bv[ni], acc[mi][ni], 0, 0, 0);
    }
  }

  #pragma unroll
  for (int ni = 0; ni < NI; ++ni) {
    const int col = col0 + wn * NW + ni * 16 + l16;
    if (col >= NSTORE) continue;
    const bool ok = (col < NREAL);
    float bvv = 0.f;
    if (BIAS) bvv = ok ? bias[col] : 0.f;
    #pragma unroll
    for (int mi = 0; mi < 4; ++mi) {
      us4 tv;
      #pragma unroll
      for (int r = 0; r < 4; ++r) {
        const long rowg = crow0 + wm * 64 + mi * 16 + q * 4 + r;
        float v = acc[mi][ni][r];
        if (BIAS) v += bvv;
        if (RELU) v = fmaxf(v, 0.f);
        if (!ok) v = 0.f;
        if (OUT_BF16) {
          const u16 v16 = f32_bf16(v);
          ((u16*)C)[rowg * (size_t)ldc + col] = v16;
          if (WT) tv[r] = v16;
        } else {
          ((float*)C)[rowg * (size_t)ldc + col] = v;
        }
      }
      if (WT) {
        const long bb = crow0 >> 9;
        const int node = (int)(crow0 & 511) + wm * 64 + mi * 16 + q * 4;
        *(us4*)(Ct + ((size_t)bb * NPH + col) * 512 + node) = tv;
      }
    }
  }
}

// dense: grid (8192/MT, Nt); XCD-aligned m-tile (gridDim.x % 8 == 0)
template <int KS, int MT, int NTILE, int NREAL, int NSTORE, bool RELU, bool BIAS,
          bool OUT_BF16, bool WT>
__global__ __launch_bounds__(256) void gemm_dense(
    const u16* __restrict__ A, const u16* __restrict__ Bt,
    const float* __restrict__ bias, void* __restrict__ C,
    u16* __restrict__ Ct, int ldc)
{
  const int x = blockIdx.x;
  const int cpx = gridDim.x >> 3;              // m-tiles per XCD
  const int mt = (x & 7) * cpx + (x >> 3);
  gemm_core<KS, MT, NTILE, NREAL, NSTORE, RELU, BIAS, OUT_BF16, WT>(
      A + (size_t)mt * MT * KS, Bt + (size_t)blockIdx.y * NTILE * KS,
      bias, C, Ct, (long)mt * MT, blockIdx.y * NTILE, ldc);
}

// batched spmm: t = L_b · B_b^T; batch b on XCD b/2 (L2-local L/Bt/C).
// R20: MT=64 -> 8 m-tiles/batch, grid 16*TPB (spmm1 1280, spmm2 1920 blocks).
template <int NP>
__global__ __launch_bounds__(256) void spmm(
    const u16* __restrict__ L, const u16* __restrict__ Bt,
    u16* __restrict__ C, int ldc)
{
  constexpr int TPB = 8 * (NP / 64);
  const int blk = blockIdx.x;
  const int xcd = blk & 7, sub = blk >> 3;
  const int b = xcd * 2 + sub / TPB;
  const int t = sub % TPB;
  const int mt = t & 7, nt = t >> 3;
  gemm_core<512, 64, 64, NP, NP, false, false, true, false>(
      L + ((size_t)b * 512 + mt * 64) * 512,
      Bt + ((size_t)b * NP + nt * 64) * 512,
      nullptr, C, nullptr, (long)b * 512 + mt * 64, nt * 64, ldc);
}

// ---------------------------------------------------------------------------
extern "C" void kernel_launch(void* const* d_in, const int* in_sizes, int n_in,
                              void* d_out, int out_size, void* d_ws, size_t ws_size,
                              hipStream_t stream) {
  const float* x4  = (const float*)d_in[0];
  const float* att = (const float*)d_in[1];
  const float* W1  = (const float*)d_in[2];
  const float* b1  = (const float*)d_in[3];
  const float* W2  = (const float*)d_in[4];
  const float* b2  = (const float*)d_in[5];
  float* out = (float*)d_out;

  char* ws = (char*)d_ws;
  f32x4* Xpad = (f32x4*)ws;                                 // 20.97 MB
  u16* ht = (u16*)ws;       ws += (size_t)ROWS * F4 * 16;   // ht (15.7 MB) aliases
                                                            // Xpad: dead after build_L
  u16* Xcat = (u16*)ws;  ws += (size_t)ROWS * KS1 * 2;      // 20.97 MB
  u16* hcat = (u16*)ws;  ws += (size_t)ROWS * KS2 * 2;      // 31.46 MB
  u16* W1t  = (u16*)ws;  ws += (size_t)1024 * KS1 * 2;      //  2.62 MB
  u16* W2t  = (u16*)ws;  ws += (size_t)640 * KS2 * 2;       //  2.46 MB
  u16* Lm   = (u16*)ws;  ws += (size_t)NB * 512 * 512 * 2;  //  8.39 MB
  u16* Xt   = (u16*)ws;  ws += (size_t)NB * NPX * 512 * 2;  // 10.49 MB
  float* att_s = (float*)ws; ws += (size_t)NB * NN * 4;     // 32 KB
  u16* order_  = (u16*)ws;   ws += (size_t)NB * NN * 2;     // 16 KB

  prep<<<dim3(3520), 256, 0, stream>>>(x4, att, W1, W2, Xpad, Xcat, Xt,
                                       W1t, W2t, order_, att_s);
  build_L<<<dim3(2048), 256, 0, stream>>>(Xpad, order_, att_s, Lm);
  spmm<NPX><<<dim3(1280), 256, 0, stream>>>(Lm, Xt, Xcat + NPX, KS1);
  // gemm1 (MT=64): grid (128,8) = 1024 blocks = 4/CU; emits hcat + ht (WT).
  gemm_dense<KS1, 64, 128, FH, NPH, true, true, true, true><<<dim3(128, 8), 256, 0, stream>>>(
      Xcat, W1t, b1, (void*)hcat, ht, KS2);
  spmm<NPH><<<dim3(1920), 256, 0, stream>>>(Lm, ht, hcat + NPH, KS2);
  // gemm2 (MT=64): grid (128,10) = 1280 blocks = 5/CU.
  gemm_dense<KS2, 64, 64, FF, FF, true, true, false, false><<<dim3(128, 10), 256, 0, stream>>>(
      hcat, W2t, b2, (void*)out, nullptr, FF);
}

// Round 15
// 218.385 us; speedup vs baseline: 1.0174x; 1.0167x over previous
//
#include <hip/hip_runtime.h>
#include <stdint.h>

typedef uint16_t u16;
typedef uint32_t u32;
typedef __attribute__((ext_vector_type(4))) float f32x4;
typedef __attribute__((ext_vector_type(4))) unsigned short us4;

#define NB   16
#define NN   512
#define FF   625      // H*W
#define FH   937      // int(625*1.5)
#define ROWS 8192     // NB*NN
#define KS1  1280     // [X(625) pad->640 | t1(625) pad->640]
#define KS2  1920     // [h(937) pad->960 | t2(937) pad->960]
#define NPX  640      // padded F   (t1 cols / Xt rows per batch)
#define NPH  960      // padded Fh  (ht rows per batch)
#define F4   160      // 640/4 f32x4 slots per padded X row
#define GQ   4        // att-adjacent rows per build_L block

using frag_ab = __attribute__((ext_vector_type(8))) short;  // 8 bf16
using frag_cd = __attribute__((ext_vector_type(4))) float;  // 4 fp32

__device__ __forceinline__ u16 f32_bf16(float f) {
  union { float f; uint32_t u; } x; x.f = f;
  uint32_t r = x.u + 0x7fffu + ((x.u >> 16) & 1u);   // RNE
  return (u16)(r >> 16);
}
__device__ __forceinline__ void gload_lds16(const void* g, void* l) {
  __builtin_amdgcn_global_load_lds((__attribute__((address_space(1))) void*)g,
                                   (__attribute__((address_space(3))) void*)l,
                                   16, 0, 0);
}

// ---------------------------------------------------------------------------
// prep (R10-proven, R14 layout): single-pass fused, sort first, unioned LDS.
//  [0,16)        att rank-sort per batch -> order[b][512], att_s[b][512]
//  [16,1040)     fused: x4 -> Xpad + Xcat(lo) + Xt in ONE pass (x4 read once)
//  [1040,2320)   W1 -> W1t [1024][KS1]
//  [2320,3520)   W2 -> W2t [640][KS2]
// ---------------------------------------------------------------------------
__global__ __launch_bounds__(256) void prep(
    const float* __restrict__ x4, const float* __restrict__ att,
    const float* __restrict__ W1, const float* __restrict__ W2,
    f32x4* __restrict__ Xpad, u16* __restrict__ Xcat, u16* __restrict__ Xt,
    u16* __restrict__ W1t, u16* __restrict__ W2t,
    u16* __restrict__ order, float* __restrict__ att_s)
{
  __shared__ __align__(16) float smem[2112];   // 8448 B, unioned across branches
  const int blk = blockIdx.x;
  const int tid = threadIdx.x;

  if (blk < 16) {
    float* a_sh = smem;
    const int b = blk;
    a_sh[tid]       = att[b * NN + tid];
    a_sh[tid + 256] = att[b * NN + tid + 256];
    __syncthreads();
    #pragma unroll
    for (int h = 0; h < 2; ++h) {
      const int i = tid + h * 256;
      const float ai = a_sh[i];
      int r = 0;
      for (int j = 0; j < NN; ++j) {
        const float aj = a_sh[j];
        r += (aj < ai) || (aj == ai && j < i);
      }
      order[(size_t)b * NN + r] = (u16)i;
      att_s[(size_t)b * NN + r] = ai;
    }
  } else if (blk < 1040) {
    float* T = smem;
    const int idx = blk - 16;
    const int xcd = idx & 7, sub = idx >> 3;    // sub 0..127
    const int b = xcd * 2 + (sub >> 6);
    const int rr = sub & 63;
    const int q = rr >> 4;                      // f-quarter 0..3
    const int nt = rr & 15;                     // node-tile 0..15
    const int node0 = nt * 32;
    const int tx = tid & 31, ty = tid >> 5;
    const int lrow = tid >> 3, lcol = tid & 7;

    int buf = 0;
    {
      const int f0 = q * 160;
      #pragma unroll
      for (int r = 0; r < 4; ++r) {
        const int node = node0 + ty + r * 8;
        const int f = f0 + tx;
        T[(ty + r * 8) * 33 + tx] = (f < FF) ? x4[((size_t)b * NN + node) * FF + f] : 0.f;
      }
    }
    __syncthreads();

    for (int c = 0; c < 5; ++c) {
      const int f0 = q * 160 + c * 32;
      float vnext[4];
      const bool has = (c + 1 < 5);
      if (has) {
        const int fn = f0 + 32 + tx;
        #pragma unroll
        for (int r = 0; r < 4; ++r) {
          const int node = node0 + ty + r * 8;
          vnext[r] = (fn < FF) ? x4[((size_t)b * NN + node) * FF + fn] : 0.f;
        }
      }
      {
        const int node_l = lrow, k4s = lcol;
        const size_t grow = (size_t)b * NN + node0 + node_l;
        const int k4 = q * 40 + c * 8 + k4s;
        f32x4 v; us4 o;
        #pragma unroll
        for (int t = 0; t < 4; ++t) {
          const float x = T[buf * 1056 + node_l * 33 + k4s * 4 + t];
          v[t] = x; o[t] = f32_bf16(x);
        }
        Xpad[grow * F4 + k4] = v;
        *(us4*)(Xcat + grow * KS1 + k4 * 4) = o;
      }
      {
        const int fl = lrow, nl = lcol;
        const int f = f0 + fl;
        us4 ov;
        #pragma unroll
        for (int t = 0; t < 4; ++t)
          ov[t] = f32_bf16(T[buf * 1056 + (nl * 4 + t) * 33 + fl]);
        *(us4*)(Xt + ((size_t)b * NPX + f) * 512 + node0 + nl * 4) = ov;
      }
      if (has) {
        #pragma unroll
        for (int r = 0; r < 4; ++r)
          T[(buf ^ 1) * 1056 + (ty + r * 8) * 33 + tx] = vnext[r];
        __syncthreads();
        buf ^= 1;
      }
    }
  } else if (blk < 2320) {
    float (*tile)[33] = (float(*)[33])smem;
    const int bb = blk - 1040;                  // 40 kt x 32 nt
    const int kt = bb % 40, nt = bb / 40;
    const int tx = tid & 31, ty = tid >> 5;
    #pragma unroll
    for (int r = 0; r < 4; ++r) {
      int k = kt * 32 + ty + r * 8;
      int n = nt * 32 + tx;
      float v = 0.f;
      int c = -1, kk = 0;
      if (k < 625) { c = 0; kk = k; }
      else if (k >= 640 && k < 1265) { c = 1; kk = k - 640; }
      if (c >= 0 && n < FH) v = W1[((size_t)c * 625 + kk) * FH + n];
      tile[ty + r * 8][tx] = v;
    }
    __syncthreads();
    #pragma unroll
    for (int r = 0; r < 4; ++r) {
      int n = nt * 32 + ty + r * 8;
      int k = kt * 32 + tx;
      W1t[(size_t)n * KS1 + k] = f32_bf16(tile[tx][ty + r * 8]);
    }
  } else {
    float (*tile)[33] = (float(*)[33])smem;
    const int bb = blk - 2320;                  // 60 kt x 20 nt
    const int kt = bb % 60, nt = bb / 60;
    const int tx = tid & 31, ty = tid >> 5;
    #pragma unroll
    for (int r = 0; r < 4; ++r) {
      int k = kt * 32 + ty + r * 8;
      int n = nt * 32 + tx;
      float v = 0.f;
      int c = -1, kk = 0;
      if (k < 937) { c = 0; kk = k; }
      else if (k >= 960 && k < 1897) { c = 1; kk = k - 960; }
      if (c >= 0 && n < FF) v = W2[((size_t)c * 937 + kk) * FF + n];
      tile[ty + r * 8][tx] = v;
    }
    __syncthreads();
    #pragma unroll
    for (int r = 0; r < 4; ++r) {
      int n = nt * 32 + ty + r * 8;
      int k = kt * 32 + tx;
      W2t[(size_t)n * KS2 + k] = f32_bf16(tile[tx][ty + r * 8]);
    }
  }
}

// ---------------------------------------------------------------------------
// build_L (R9-proven): att-sorted row grouping, GQ=4 rows/block, contiguous
// sorted candidate window + exact per-row recheck. Xj loaded once per 4 rows.
// ---------------------------------------------------------------------------
__global__ __launch_bounds__(256) void build_L(
    const f32x4* __restrict__ Xpad,   // [ROWS][160]
    const u16* __restrict__ order,    // [NB][512]
    const float* __restrict__ att_s,  // [NB][512] ascending
    u16* __restrict__ L)              // [NB][512][512] bf16 row-major
{
  __shared__ float atts[512];
  __shared__ u16 ords[512];
  __shared__ u16 cand[512];
  __shared__ u16 flag[GQ][512];
  __shared__ int ncand, naccs[GQ];

  const int tid = threadIdx.x;
  const int blk = blockIdx.x;
  const int xcd = blk & 7, sub = blk >> 3;     // sub 0..255
  const int b = xcd * 2 + (sub >> 7);
  const int p0 = (sub & 127) * GQ;
  const f32x4* Xb4 = Xpad + (size_t)b * NN * F4;

  atts[tid]       = att_s[b * NN + tid];
  atts[tid + 256] = att_s[b * NN + tid + 256];
  ords[tid]       = order[b * NN + tid];
  ords[tid + 256] = order[b * NN + tid + 256];
  {
    u32* fz = (u32*)&flag[0][0];               // GQ*512 u16 = 1024 u32
    #pragma unroll
    for (int s = 0; s < GQ; ++s) fz[tid + s * 256] = 0;
  }
  if (tid == 0) ncand = 0;
  if (tid < GQ) naccs[tid] = 0;
  __syncthreads();

  float av[GQ]; int ig[GQ];
  #pragma unroll
  for (int g = 0; g < GQ; ++g) { av[g] = atts[p0 + g]; ig[g] = ords[p0 + g]; }
  if (tid < GQ) flag[tid][ords[p0 + tid]] = 1;   // self (A+I diagonal)

  {
    const float lo = av[0] - 0.0501f, hi = av[GQ - 1] + 0.0501f;
    const bool q0 = (atts[tid] >= lo) && (atts[tid] <= hi);
    const bool q1 = (atts[tid + 256] >= lo) && (atts[tid + 256] <= hi);
    const unsigned long long m0 = __ballot(q0);
    const unsigned long long m1 = __ballot(q1);
    const int c0 = __popcll(m0);
    const int c1 = __popcll(m1);
    const int lane = tid & 63;
    int base = 0;
    if (lane == 0 && (c0 + c1)) base = atomicAdd(&ncand, c0 + c1);
    base = __shfl(base, 0, 64);
    const unsigned long long below = (1ull << lane) - 1ull;
    if (q0) cand[base + __popcll(m0 & below)] = (u16)tid;
    if (q1) cand[base + c0 + __popcll(m1 & below)] = (u16)(tid + 256);
  }
  __syncthreads();
  const int nc = ncand;

  const int hl = tid & 31;
  const int hw = tid >> 5;

  f32x4 xi[GQ][5];
  #pragma unroll
  for (int g = 0; g < GQ; ++g) {
    const f32x4* Xi = Xb4 + (size_t)ig[g] * F4;
    #pragma unroll
    for (int s = 0; s < 5; ++s) xi[g][s] = Xi[s * 32 + hl];
  }

  for (int c = hw; c < nc; c += 8) {
    const int p = cand[c];
    const int j = ords[p];
    const float aj = atts[p];
    const f32x4* Xj = Xb4 + (size_t)j * F4;
    f32x4 xj[5];
    #pragma unroll
    for (int s = 0; s < 5; ++s) xj[s] = Xj[s * 32 + hl];

    float pd[GQ];
    #pragma unroll
    for (int g = 0; g < GQ; ++g) {
      float p2 = 0.f;   // EXACT summation order of the original per-row kernel
      #pragma unroll
      for (int t = 0; t < 4; ++t) {
        p2 += fabsf(xi[g][0][t] - xj[0][t]) + fabsf(xi[g][1][t] - xj[1][t])
            + fabsf(xi[g][2][t] - xj[2][t]) + fabsf(xi[g][3][t] - xj[3][t])
            + fabsf(xi[g][4][t] - xj[4][t]);
      }
      pd[g] = p2;
    }
    #pragma unroll
    for (int off = 16; off; off >>= 1) {
      #pragma unroll
      for (int g = 0; g < GQ; ++g) pd[g] += __shfl_xor(pd[g], off, 64);
    }
    if (hl == 0) {
      #pragma unroll
      for (int g = 0; g < GQ; ++g) {
        if (pd[g] <= 180.0f && fabsf(av[g] - aj) <= 0.05f && j != ig[g]) {
          flag[g][j] = 1;
          atomicAdd(&naccs[g], 1);
        }
      }
    }
  }
  __syncthreads();

  #pragma unroll
  for (int g = 0; g < GQ; ++g) {
    const u16 dv = f32_bf16(1.0f / (float)(naccs[g] + 1));
    const long row = (long)b * NN + ig[g];
    const u32 lo2 = flag[g][2 * tid]     ? (u32)dv : 0u;
    const u32 hi2 = flag[g][2 * tid + 1] ? (u32)dv : 0u;
    *(u32*)(L + (size_t)row * 512 + 2 * tid) = lo2 | (hi2 << 16);
  }
}

// ---------------------------------------------------------------------------
// gemm1_dp (R21): MT=128 x NTILE=128, 256 threads / 4 waves (R14 wave map),
// LDS double-buffered 64KB -> EXACTLY 2 blocks/CU (grid 512). Counted
// s_waitcnt vmcnt(8) + raw s_barrier: tile k+1's 8 loads stay in flight
// through the wait (drains to 0 only at the last K-step). This is the last
// untested cell of {pipeline-depth x blocks/CU}: R15 = dbuf+drain0 (null),
// R19 = counted-vmcnt at 1 blk/CU (null), R16/R20 = TLP-only (null).
// Fragment math / swizzle / epilogue identical to R14's gemm1 (bit-identical
// accumulation order). Emits hcat + ht (WT).
// ---------------------------------------------------------------------------
__global__ __launch_bounds__(256) void gemm1_dp(
    const u16* __restrict__ A,       // Xcat [8192][1280]
    const u16* __restrict__ Bt,      // W1t  [1024][1280]
    const float* __restrict__ bias, u16* __restrict__ C,   // hcat, ldc=KS2
    u16* __restrict__ Ct)            // ht [NB][960][512]
{
  __shared__ __align__(16) u16 Ash[2][128 * 64];   // 32 KB
  __shared__ __align__(16) u16 Bsh[2][128 * 64];   // 32 KB

  const int tid  = threadIdx.x;
  const int lane = tid & 63;
  const int wave = tid >> 6;
  const int wm = wave & 1, wn = wave >> 1;
  const int q = lane >> 4, l16 = lane & 15;

  const int x = blockIdx.x;
  const int mt = ((x & 7) << 3) | (x >> 3);   // XCD-aligned m-tile
  const int nt = blockIdx.y;
  const u16* At  = A  + (size_t)mt * 128 * KS1;
  const u16* Btt = Bt + (size_t)nt * 128 * KS1;

  const u16* pa[4]; const u16* pb[4];
  #pragma unroll
  for (int r = 0; r < 4; ++r) {
    const int ci = r * 256 + tid;
    const int row = ci >> 3, cpos = ci & 7;
    pa[r] = At  + (size_t)row * KS1 + (cpos ^ (row & 7)) * 8;
    pb[r] = Btt + (size_t)row * KS1 + (cpos ^ (row & 7)) * 8;
  }
  const int wbase = (tid & 192) * 8;

  int aoff[4][2], boff[4][2];
  #pragma unroll
  for (int mi = 0; mi < 4; ++mi) {
    const int row = wm * 64 + mi * 16 + l16;
    aoff[mi][0] = row * 64 + ((q    ) ^ (l16 & 7)) * 8;
    aoff[mi][1] = row * 64 + ((q + 4) ^ (l16 & 7)) * 8;
  }
  #pragma unroll
  for (int ni = 0; ni < 4; ++ni) {
    const int row = wn * 64 + ni * 16 + l16;
    boff[ni][0] = row * 64 + ((q    ) ^ (l16 & 7)) * 8;
    boff[ni][1] = row * 64 + ((q + 4) ^ (l16 & 7)) * 8;
  }

  frag_cd acc[4][4] = {};
  constexpr int KT = KS1 / 64;        // 20

  // prologue: stage tile 0 -> buf0, tile 1 -> buf1 (16 loads in flight)
  #pragma unroll
  for (int r = 0; r < 4; ++r) {
    gload_lds16(pa[r], &Ash[0][r * 2048 + wbase]); pa[r] += 64;
    gload_lds16(pb[r], &Bsh[0][r * 2048 + wbase]); pb[r] += 64;
  }
  #pragma unroll
  for (int r = 0; r < 4; ++r) {
    gload_lds16(pa[r], &Ash[1][r * 2048 + wbase]); pa[r] += 64;
    gload_lds16(pb[r], &Bsh[1][r * 2048 + wbase]); pb[r] += 64;
  }

  for (int kt = 0; kt < KT; ++kt) {
    const int cur = kt & 1;
    // tile kt landed when <=8 outstanding (FIFO; the 8 are tile kt+1's).
    if (kt + 1 < KT) asm volatile("s_waitcnt vmcnt(8)" ::: "memory");
    else             asm volatile("s_waitcnt vmcnt(0)" ::: "memory");
    __builtin_amdgcn_s_barrier();        // all waves' tile-kt data in LDS
    __builtin_amdgcn_sched_barrier(0);

    const u16* A0 = &Ash[cur][0];
    const u16* B0 = &Bsh[cur][0];
    __builtin_amdgcn_s_setprio(1);
    #pragma unroll
    for (int kk = 0; kk < 2; ++kk) {
      frag_ab av[4], bv[4];
      #pragma unroll
      for (int mi = 0; mi < 4; ++mi) av[mi] = *(const frag_ab*)&A0[aoff[mi][kk]];
      #pragma unroll
      for (int ni = 0; ni < 4; ++ni) bv[ni] = *(const frag_ab*)&B0[boff[ni][kk]];
      #pragma unroll
      for (int mi = 0; mi < 4; ++mi)
        #pragma unroll
        for (int ni = 0; ni < 4; ++ni)
          acc[mi][ni] = __builtin_amdgcn_mfma_f32_16x16x32_bf16(
              av[mi], bv[ni], acc[mi][ni], 0, 0, 0);
    }
    __builtin_amdgcn_s_setprio(0);
    __builtin_amdgcn_sched_barrier(0);
    __builtin_amdgcn_s_barrier();        // all reads of buf[cur] done
    if (kt + 2 < KT) {                   // stage tile kt+2 into freed buf
      #pragma unroll
      for (int r = 0; r < 4; ++r) {
        gload_lds16(pa[r], &Ash[cur][r * 2048 + wbase]); pa[r] += 64;
        gload_lds16(pb[r], &Bsh[cur][r * 2048 + wbase]); pb[r] += 64;
      }
    }
  }

  // epilogue (R14 gemm1): bias + relu + bf16 into hcat, transposed into ht
  const int col0 = nt * 128;
  const long crow0 = (long)mt * 128;
  const long bb = crow0 >> 9;
  #pragma unroll
  for (int ni = 0; ni < 4; ++ni) {
    const int col = col0 + wn * 64 + ni * 16 + l16;
    if (col >= NPH) continue;
    const bool ok = (col < FH);
    const float bvv = ok ? bias[col] : 0.f;
    #pragma unroll
    for (int mi = 0; mi < 4; ++mi) {
      us4 tv;
      #pragma unroll
      for (int r = 0; r < 4; ++r) {
        const long rowg = crow0 + wm * 64 + mi * 16 + q * 4 + r;
        float v = acc[mi][ni][r];
        v += bvv;
        v = fmaxf(v, 0.f);
        if (!ok) v = 0.f;
        const u16 v16 = f32_bf16(v);
        C[rowg * (size_t)KS2 + col] = v16;
        tv[r] = v16;
      }
      const int node = (int)(crow0 & 511) + wm * 64 + mi * 16 + q * 4;
      *(us4*)(Ct + ((size_t)bb * NPH + col) * 512 + node) = tv;
    }
  }
}

// ---------------------------------------------------------------------------
// gemm_core (R14-proven single-buffer schedule). 128M x NTILE-N tile, BK=64,
// XOR chunk swizzle. Epilogue: store cols < NSTORE; value = col<NREAL ?
// f(acc) : 0. WT: also store bf16 transposed per batch into Ct.
// ---------------------------------------------------------------------------
template <int KS, int NTILE, int NREAL, int NSTORE, bool RELU, bool BIAS,
          bool OUT_BF16, bool WT>
__device__ __forceinline__ void gemm_core(
    const u16* __restrict__ At,      // A tile base: rows 0..127, stride KS
    const u16* __restrict__ Btt,     // B^T tile base: rows 0..NTILE-1, stride KS
    const float* __restrict__ bias, void* __restrict__ C,
    u16* __restrict__ Ct,            // transposed out (WT only)
    long crow0, int col0, int ldc)
{
  constexpr int NI = NTILE / 32;
  constexpr int BR = NTILE / 32;
  __shared__ __align__(16) u16 Ash[128 * 64];
  __shared__ __align__(16) u16 Bsh[NTILE * 64];

  const int tid  = threadIdx.x;
  const int lane = tid & 63;
  const int wave = tid >> 6;
  const int wm = wave & 1, wn = wave >> 1;
  const int q = lane >> 4, l16 = lane & 15;

  const u16* pa[4]; const u16* pb[BR];
  #pragma unroll
  for (int r = 0; r < 4; ++r) {
    const int ci = r * 256 + tid;
    const int row = ci >> 3, cpos = ci & 7;
    pa[r] = At + (size_t)row * KS + (cpos ^ (row & 7)) * 8;
  }
  #pragma unroll
  for (int r = 0; r < BR; ++r) {
    const int ci = r * 256 + tid;
    const int row = ci >> 3, cpos = ci & 7;
    pb[r] = Btt + (size_t)row * KS + (cpos ^ (row & 7)) * 8;
  }
  const int wbase = (tid & 192) * 8;

  const frag_ab* fA[4][2]; const frag_ab* fB[NI][2];
  #pragma unroll
  for (int mi = 0; mi < 4; ++mi) {
    const int row = wm * 64 + mi * 16 + l16;
    fA[mi][0] = (const frag_ab*)&Ash[row * 64 + ((q    ) ^ (l16 & 7)) * 8];
    fA[mi][1] = (const frag_ab*)&Ash[row * 64 + ((q + 4) ^ (l16 & 7)) * 8];
  }
  #pragma unroll
  for (int ni = 0; ni < NI; ++ni) {
    const int row = wn * (NTILE / 2) + ni * 16 + l16;
    fB[ni][0] = (const frag_ab*)&Bsh[row * 64 + ((q    ) ^ (l16 & 7)) * 8];
    fB[ni][1] = (const frag_ab*)&Bsh[row * 64 + ((q + 4) ^ (l16 & 7)) * 8];
  }

  frag_cd acc[4][NI] = {};

  constexpr int KT = KS / 64;
  for (int kt = 0; kt < KT; ++kt) {
    __syncthreads();
    #pragma unroll
    for (int r = 0; r < 4; ++r) { gload_lds16(pa[r], &Ash[r * 2048 + wbase]); pa[r] += 64; }
    #pragma unroll
    for (int r = 0; r < BR; ++r) { gload_lds16(pb[r], &Bsh[r * 2048 + wbase]); pb[r] += 64; }
    __syncthreads();

    #pragma unroll
    for (int kk = 0; kk < 2; ++kk) {
      frag_ab av[4], bv[NI];
      #pragma unroll
      for (int mi = 0; mi < 4; ++mi) av[mi] = *fA[mi][kk];
      #pragma unroll
      for (int ni = 0; ni < NI; ++ni) bv[ni] = *fB[ni][kk];
      #pragma unroll
      for (int mi = 0; mi < 4; ++mi)
        #pragma unroll
        for (int ni = 0; ni < NI; ++ni)
          acc[mi][ni] = __builtin_amdgcn_mfma_f32_16x16x32_bf16(
              av[mi], bv[ni], acc[mi][ni], 0, 0, 0);
    }
  }

  #pragma unroll
  for (int ni = 0; ni < NI; ++ni) {
    const int col = col0 + wn * (NTILE / 2) + ni * 16 + l16;
    if (col >= NSTORE) continue;
    const bool ok = (col < NREAL);
    float bvv = 0.f;
    if (BIAS) bvv = ok ? bias[col] : 0.f;
    #pragma unroll
    for (int mi = 0; mi < 4; ++mi) {
      us4 tv;
      #pragma unroll
      for (int r = 0; r < 4; ++r) {
        const long rowg = crow0 + wm * 64 + mi * 16 + q * 4 + r;
        float v = acc[mi][ni][r];
        if (BIAS) v += bvv;
        if (RELU) v = fmaxf(v, 0.f);
        if (!ok) v = 0.f;
        if (OUT_BF16) {
          const u16 v16 = f32_bf16(v);
          ((u16*)C)[rowg * (size_t)ldc + col] = v16;
          if (WT) tv[r] = v16;
        } else {
          ((float*)C)[rowg * (size_t)ldc + col] = v;
        }
      }
      if (WT) {
        const long bb = crow0 >> 9;
        const int node = (int)(crow0 & 511) + wm * 64 + mi * 16 + q * 4;
        *(us4*)(Ct + ((size_t)bb * NPH + col) * 512 + node) = tv;
      }
    }
  }
}

// dense: grid (64, Nt); XCD-aligned m-tile (R6)
template <int KS, int NTILE, int NREAL, int NSTORE, bool RELU, bool BIAS,
          bool OUT_BF16, bool WT>
__global__ __launch_bounds__(256) void gemm_dense(
    const u16* __restrict__ A, const u16* __restrict__ Bt,
    const float* __restrict__ bias, void* __restrict__ C,
    u16* __restrict__ Ct, int ldc)
{
  const int x = blockIdx.x;
  const int mt = ((x & 7) << 3) | (x >> 3);
  gemm_core<KS, NTILE, NREAL, NSTORE, RELU, BIAS, OUT_BF16, WT>(
      A + (size_t)mt * 128 * KS, Bt + (size_t)blockIdx.y * NTILE * KS,
      bias, C, Ct, (long)mt * 128, blockIdx.y * NTILE, ldc);
}

// batched spmm: t = L_b · B_b^T; batch b on XCD b/2 (L2-local L/Bt/C).
template <int NP>
__global__ __launch_bounds__(256) void spmm(
    const u16* __restrict__ L, const u16* __restrict__ Bt,
    u16* __restrict__ C, int ldc)
{
  constexpr int TPB = 4 * (NP / 64);
  const int blk = blockIdx.x;
  const int xcd = blk & 7, sub = blk >> 3;
  const int b = xcd * 2 + sub / TPB;
  const int t = sub % TPB;
  const int mt = t & 3, nt = t >> 2;
  gemm_core<512, 64, NP, NP, false, false, true, false>(
      L + ((size_t)b * 512 + mt * 128) * 512,
      Bt + ((size_t)b * NP + nt * 64) * 512,
      nullptr, C, nullptr, (long)b * 512 + mt * 128, nt * 64, ldc);
}

// ---------------------------------------------------------------------------
extern "C" void kernel_launch(void* const* d_in, const int* in_sizes, int n_in,
                              void* d_out, int out_size, void* d_ws, size_t ws_size,
                              hipStream_t stream) {
  const float* x4  = (const float*)d_in[0];
  const float* att = (const float*)d_in[1];
  const float* W1  = (const float*)d_in[2];
  const float* b1  = (const float*)d_in[3];
  const float* W2  = (const float*)d_in[4];
  const float* b2  = (const float*)d_in[5];
  float* out = (float*)d_out;

  char* ws = (char*)d_ws;
  f32x4* Xpad = (f32x4*)ws;                                 // 20.97 MB
  u16* ht = (u16*)ws;       ws += (size_t)ROWS * F4 * 16;   // ht (15.7 MB) aliases
                                                            // Xpad: dead after build_L
  u16* Xcat = (u16*)ws;  ws += (size_t)ROWS * KS1 * 2;      // 20.97 MB
  u16* hcat = (u16*)ws;  ws += (size_t)ROWS * KS2 * 2;      // 31.46 MB
  u16* W1t  = (u16*)ws;  ws += (size_t)1024 * KS1 * 2;      //  2.62 MB
  u16* W2t  = (u16*)ws;  ws += (size_t)640 * KS2 * 2;       //  2.46 MB
  u16* Lm   = (u16*)ws;  ws += (size_t)NB * 512 * 512 * 2;  //  8.39 MB
  u16* Xt   = (u16*)ws;  ws += (size_t)NB * NPX * 512 * 2;  // 10.49 MB
  float* att_s = (float*)ws; ws += (size_t)NB * NN * 4;     // 32 KB
  u16* order_  = (u16*)ws;   ws += (size_t)NB * NN * 2;     // 16 KB

  prep<<<dim3(3520), 256, 0, stream>>>(x4, att, W1, W2, Xpad, Xcat, Xt,
                                       W1t, W2t, order_, att_s);
  build_L<<<dim3(2048), 256, 0, stream>>>(Xpad, order_, att_s, Lm);
  spmm<NPX><<<dim3(640), 256, 0, stream>>>(Lm, Xt, Xcat + NPX, KS1);
  // gemm1 (R21): counted-vmcnt deep pipeline at 2 blocks/CU; emits hcat + ht.
  gemm1_dp<<<dim3(64, 8), 256, 0, stream>>>(Xcat, W1t, b1, hcat, ht);
  spmm<NPH><<<dim3(960), 256, 0, stream>>>(Lm, ht, hcat + NPH, KS2);
  gemm_dense<KS2, 64, FF, FF, true, true, false, false><<<dim3(64, 10), 256, 0, stream>>>(
      hcat, W2t, b2, (void*)out, nullptr, FF);
}